// Round 1
// baseline (2164.026 us; speedup 1.0000x reference)
//
#include <hip/hip_runtime.h>

#define RESN 100
#define BETAC 0.1f

// ws layout (floats):
// [0]=S (sum init_conc), [1]=maxdiff(t_init), [2]=tmin, [3]=tmax
// [16 .. 16+R)          kp
// [16+R .. 16+2R)       km
// [16+2R .. 16+6R)      idx (int4 per row: neg0, neg1, pos0, pos1)
// [16+6R .. +RESN*C)    curve (RESN x C)

__global__ void scalars_kernel(const float* __restrict__ init_conc, int Cn,
                               const float* __restrict__ t_init, int TN,
                               float* __restrict__ ws) {
    __shared__ float red[256];
    int tid = threadIdx.x;

    float s = 0.f;
    for (int i = tid; i < Cn; i += 256) s += init_conc[i];
    red[tid] = s; __syncthreads();
    for (int o = 128; o; o >>= 1) { if (tid < o) red[tid] += red[tid + o]; __syncthreads(); }
    float S = red[0]; __syncthreads();

    float md = -1e30f;
    for (int i = tid; i < TN - 1; i += 256) md = fmaxf(md, t_init[i + 1] - t_init[i]);
    red[tid] = md; __syncthreads();
    for (int o = 128; o; o >>= 1) { if (tid < o) red[tid] = fmaxf(red[tid], red[tid + o]); __syncthreads(); }
    float MD = red[0]; __syncthreads();

    float mn = 1e30f;
    for (int i = tid; i < TN; i += 256) mn = fminf(mn, t_init[i]);
    red[tid] = mn; __syncthreads();
    for (int o = 128; o; o >>= 1) { if (tid < o) red[tid] = fminf(red[tid], red[tid + o]); __syncthreads(); }
    float TMIN = red[0]; __syncthreads();

    float mx = -1e30f;
    for (int i = tid; i < TN; i += 256) mx = fmaxf(mx, t_init[i]);
    red[tid] = mx; __syncthreads();
    for (int o = 128; o; o >>= 1) { if (tid < o) red[tid] = fmaxf(red[tid], red[tid + o]); __syncthreads(); }
    float TMAX = red[0];

    if (tid == 0) { ws[0] = S; ws[1] = MD; ws[2] = TMIN; ws[3] = TMAX; }
}

// One block per reaction row: find the 2 reactant (nu<0) and 2 product (nu>0)
// columns, compute order sums, then kp/km via smooth_clamp.
__global__ void extract_kernel(const float* __restrict__ nu,
                               const float* __restrict__ f,
                               const float* __restrict__ r,
                               int Rn, int Cn, int TN,
                               float* __restrict__ ws) {
    int row = blockIdx.x;
    int tid = threadIdx.x;
    __shared__ int cntn, cntp;
    __shared__ int negi[2], posi[2];
    __shared__ float red[256];
    if (tid == 0) { cntn = 0; cntp = 0; }
    __syncthreads();

    float sp = 0.f, sn = 0.f;
    const float* nr = nu + (size_t)row * Cn;
    for (int c = tid; c < Cn; c += 256) {
        float v = nr[c];
        if (v < 0.f) {
            int p = atomicAdd(&cntn, 1);
            if (p < 2) negi[p] = c;
            sn -= v;
        } else if (v > 0.f) {
            int p = atomicAdd(&cntp, 1);
            if (p < 2) posi[p] = c;
            sp += v;
        }
    }
    red[tid] = sp; __syncthreads();
    for (int o = 128; o; o >>= 1) { if (tid < o) red[tid] += red[tid + o]; __syncthreads(); }
    float order_f = red[0]; __syncthreads();
    red[tid] = sn; __syncthreads();
    for (int o = 128; o; o >>= 1) { if (tid < o) red[tid] += red[tid + o]; __syncthreads(); }
    float order_r = red[0]; __syncthreads();

    if (tid == 0) {
        float S = ws[0], MD = ws[1];
        float base = (float)TN * 10.0f / MD;
        float ub0 = base / powf(S, order_f - 1.0f);
        float ub1 = base / powf(S, order_r - 1.0f);
        // smooth_clamp(x, 0, ub) = ub * sigmoid(BETA*(x - ub/2))
        float kp = ub0 / (1.0f + expf(-BETAC * (f[row] - 0.5f * ub0)));
        float km = ub1 / (1.0f + expf(-BETAC * (r[row] - 0.5f * ub1)));
        ws[16 + row] = kp;
        ws[16 + Rn + row] = km;
        int* idx = (int*)(ws + 16 + 2 * Rn);
        idx[4 * row + 0] = negi[0];
        idx[4 * row + 1] = negi[1];
        idx[4 * row + 2] = posi[0];
        idx[4 * row + 3] = posi[1];
    }
}

// Single-block Euler integration: state C (2048) in LDS, 99 steps, sparse
// rate scatter via LDS float atomics. Writes the full trajectory to `curve`.
__global__ void __launch_bounds__(1024) integrate_kernel(
    const float* __restrict__ init_conc, int Cn, int Rn,
    const float* __restrict__ ws, float* __restrict__ curve) {
    __shared__ float Cls[2048];   // clipped state for rate reads
    __shared__ float dC[2048];    // accumulator
    int tid = threadIdx.x;

    const int4*  idx4   = (const int4*)(ws + 16 + 2 * Rn);
    const float* kp_arr = ws + 16;
    const float* km_arr = ws + 16 + Rn;

    int i1[4], i2[4], j1[4], j2[4];
    float kpv[4], kmv[4];
#pragma unroll
    for (int k = 0; k < 4; k++) {
        int rr = tid + k * 1024;
        int4 v = idx4[rr];
        i1[k] = v.x; i2[k] = v.y; j1[k] = v.z; j2[k] = v.w;
        kpv[k] = kp_arr[rr];
        kmv[k] = km_arr[rr];
    }

    float Creg[2];
#pragma unroll
    for (int k = 0; k < 2; k++) {
        int s = tid + k * 1024;
        float v = init_conc[s];
        Creg[k] = v;
        Cls[s] = fminf(fmaxf(v, 1e-8f), 1000.f);
        dC[s] = 0.f;
        curve[s] = v;  // row 0 = init_conc
    }
    float tmin = ws[2], tmax = ws[3];
    float dt = (tmax - tmin) / (float)(RESN - 1);
    __syncthreads();

    for (int stp = 0; stp < RESN - 1; ++stp) {
#pragma unroll
        for (int k = 0; k < 4; k++) {
            float rate = kpv[k] * Cls[i1[k]] * Cls[i2[k]]
                       - kmv[k] * Cls[j1[k]] * Cls[j2[k]];
            atomicAdd(&dC[i1[k]], -rate);
            atomicAdd(&dC[i2[k]], -rate);
            atomicAdd(&dC[j1[k]],  rate);
            atomicAdd(&dC[j2[k]],  rate);
        }
        __syncthreads();
#pragma unroll
        for (int k = 0; k < 2; k++) {
            int s = tid + k * 1024;
            Creg[k] += dC[s] * dt;
            Cls[s] = fminf(fmaxf(Creg[k], 1e-8f), 1000.f);
            dC[s] = 0.f;
            curve[(size_t)(stp + 1) * 2048 + s] = Creg[k];
        }
        __syncthreads();
    }
}

// One block per query time: lerp between the two bracketing trajectory rows.
__global__ void __launch_bounds__(256) interp_kernel(
    const float* __restrict__ t, const float* __restrict__ curve,
    const float* __restrict__ ws, float* __restrict__ out, int Cn) {
    int q = blockIdx.x;
    float tq = t[q];
    float tmin = ws[2], tmax = ws[3];
    float h = (tmax - tmin) / (float)(RESN - 1);
    float u = (tq - tmin) / h;
    int j0 = (int)floorf(u);
    if (j0 < 0) j0 = 0;
    if (j0 > RESN - 2) j0 = RESN - 2;
    float w = u - (float)j0;
    w = fminf(fmaxf(w, 0.f), 1.f);

    const float4* r0 = (const float4*)(curve + (size_t)j0 * Cn);
    const float4* r1 = (const float4*)(curve + (size_t)(j0 + 1) * Cn);
    float4* o = (float4*)(out + (size_t)q * Cn);
    int n4 = Cn >> 2;
    for (int k = threadIdx.x; k < n4; k += 256) {
        float4 a = r0[k], b = r1[k];
        float4 res;
        res.x = a.x + (b.x - a.x) * w;
        res.y = a.y + (b.y - a.y) * w;
        res.z = a.z + (b.z - a.z) * w;
        res.w = a.w + (b.w - a.w) * w;
        o[k] = res;
    }
}

extern "C" void kernel_launch(void* const* d_in, const int* in_sizes, int n_in,
                              void* d_out, int out_size, void* d_ws, size_t ws_size,
                              hipStream_t stream) {
    const float* t         = (const float*)d_in[0];
    const float* f         = (const float*)d_in[1];
    const float* r         = (const float*)d_in[2];
    const float* nu        = (const float*)d_in[3];
    const float* init_conc = (const float*)d_in[4];
    const float* t_init    = (const float*)d_in[5];
    int TQ = in_sizes[0];
    int Rn = in_sizes[1];
    int Cn = in_sizes[4];
    int TN = in_sizes[5];

    float* ws = (float*)d_ws;
    float* curve = ws + 16 + 6 * (size_t)Rn;

    hipLaunchKernelGGL(scalars_kernel, dim3(1), dim3(256), 0, stream,
                       init_conc, Cn, t_init, TN, ws);
    hipLaunchKernelGGL(extract_kernel, dim3(Rn), dim3(256), 0, stream,
                       nu, f, r, Rn, Cn, TN, ws);
    hipLaunchKernelGGL(integrate_kernel, dim3(1), dim3(1024), 0, stream,
                       init_conc, Cn, Rn, ws, curve);
    hipLaunchKernelGGL(interp_kernel, dim3(TQ), dim3(256), 0, stream,
                       t, curve, ws, (float*)d_out, Cn);
}

// Round 2
// 458.697 us; speedup vs baseline: 4.7178x; 4.7178x over previous
//
#include <hip/hip_runtime.h>

#define RESN 100
#define BETAC 0.1f

// ws layout (floats):
// [0]=S (sum init_conc), [1]=maxdiff(t_init), [2]=tmin, [3]=tmax
// [16 .. 16+R)          kp
// [16+R .. 16+2R)       km
// [16+2R .. 16+6R)      idx (int4 per row: neg0, neg1, pos0, pos1)
// [16+6R .. +RESN*C)    curve (RESN x C)

__global__ void scalars_kernel(const float* __restrict__ init_conc, int Cn,
                               const float* __restrict__ t_init, int TN,
                               float* __restrict__ ws) {
    __shared__ float red[256];
    int tid = threadIdx.x;

    float s = 0.f;
    for (int i = tid; i < Cn; i += 256) s += init_conc[i];
    red[tid] = s; __syncthreads();
    for (int o = 128; o; o >>= 1) { if (tid < o) red[tid] += red[tid + o]; __syncthreads(); }
    float S = red[0]; __syncthreads();

    float md = -1e30f;
    for (int i = tid; i < TN - 1; i += 256) md = fmaxf(md, t_init[i + 1] - t_init[i]);
    red[tid] = md; __syncthreads();
    for (int o = 128; o; o >>= 1) { if (tid < o) red[tid] = fmaxf(red[tid], red[tid + o]); __syncthreads(); }
    float MD = red[0]; __syncthreads();

    float mn = 1e30f;
    for (int i = tid; i < TN; i += 256) mn = fminf(mn, t_init[i]);
    red[tid] = mn; __syncthreads();
    for (int o = 128; o; o >>= 1) { if (tid < o) red[tid] = fminf(red[tid], red[tid + o]); __syncthreads(); }
    float TMIN = red[0]; __syncthreads();

    float mx = -1e30f;
    for (int i = tid; i < TN; i += 256) mx = fmaxf(mx, t_init[i]);
    red[tid] = mx; __syncthreads();
    for (int o = 128; o; o >>= 1) { if (tid < o) red[tid] = fmaxf(red[tid], red[tid + o]); __syncthreads(); }
    float TMAX = red[0];

    if (tid == 0) { ws[0] = S; ws[1] = MD; ws[2] = TMIN; ws[3] = TMAX; }
}

// One block per reaction row: find the 2 reactant (nu<0) and 2 product (nu>0)
// columns, compute order sums, then kp/km via smooth_clamp.
__global__ void extract_kernel(const float* __restrict__ nu,
                               const float* __restrict__ f,
                               const float* __restrict__ r,
                               int Rn, int Cn, int TN,
                               float* __restrict__ ws) {
    int row = blockIdx.x;
    int tid = threadIdx.x;
    __shared__ int cntn, cntp;
    __shared__ int negi[2], posi[2];
    __shared__ float red[256];
    if (tid == 0) { cntn = 0; cntp = 0; }
    __syncthreads();

    float sp = 0.f, sn = 0.f;
    const float* nr = nu + (size_t)row * Cn;
    for (int c = tid; c < Cn; c += 256) {
        float v = nr[c];
        if (v < 0.f) {
            int p = atomicAdd(&cntn, 1);
            if (p < 2) negi[p] = c;
            sn -= v;
        } else if (v > 0.f) {
            int p = atomicAdd(&cntp, 1);
            if (p < 2) posi[p] = c;
            sp += v;
        }
    }
    red[tid] = sp; __syncthreads();
    for (int o = 128; o; o >>= 1) { if (tid < o) red[tid] += red[tid + o]; __syncthreads(); }
    float order_f = red[0]; __syncthreads();
    red[tid] = sn; __syncthreads();
    for (int o = 128; o; o >>= 1) { if (tid < o) red[tid] += red[tid + o]; __syncthreads(); }
    float order_r = red[0]; __syncthreads();

    if (tid == 0) {
        float S = ws[0], MD = ws[1];
        float base = (float)TN * 10.0f / MD;
        float ub0 = base / powf(S, order_f - 1.0f);
        float ub1 = base / powf(S, order_r - 1.0f);
        float kp = ub0 / (1.0f + expf(-BETAC * (f[row] - 0.5f * ub0)));
        float km = ub1 / (1.0f + expf(-BETAC * (r[row] - 0.5f * ub1)));
        ws[16 + row] = kp;
        ws[16 + Rn + row] = km;
        int* idx = (int*)(ws + 16 + 2 * Rn);
        idx[4 * row + 0] = negi[0];
        idx[4 * row + 1] = negi[1];
        idx[4 * row + 2] = posi[0];
        idx[4 * row + 3] = posi[1];
    }
}

// Single-block Euler integration, gather formulation (no float atomics in the
// hot loop). One-time in-LDS CSR build (species -> contributing reactions),
// counts padded to multiples of 4 so the gather runs 4-wide via ds_read_b128
// with 4 independent rate-read chains.
#define DUMMY_RATE_SLOT 4096

__global__ void __launch_bounds__(1024) integrate_kernel(
    const float* __restrict__ init_conc, int Cn, int Rn,
    const float* __restrict__ ws, float* __restrict__ curve) {
    __shared__ __align__(16) int   csr[22532];   // padded CSR entries: (r<<1)|is_reactant
    __shared__ __align__(16) float rate[4104];   // [0..4095] rates, [4096] = 0 (dummy)
    __shared__ __align__(16) float Cls[2048];    // clipped state
    __shared__ __align__(16) int   scratch[4096];// cnt / scan ping-pong / fill
    __shared__ int soff[2049];

    int tid = threadIdx.x;

    const int4*  idx4   = (const int4*)(ws + 16 + 2 * Rn);
    const float* kp_arr = ws + 16;
    const float* km_arr = ws + 16 + Rn;

    int i1[4], i2[4], j1[4], j2[4];
    float kpv[4], kmv[4];
#pragma unroll
    for (int k = 0; k < 4; k++) {
        int rr = tid + k * 1024;
        int4 v = idx4[rr];
        i1[k] = v.x; i2[k] = v.y; j1[k] = v.z; j2[k] = v.w;
        kpv[k] = kp_arr[rr];
        kmv[k] = km_arr[rr];
    }

    // ---- CSR build (one-time) ----
    scratch[tid] = 0; scratch[tid + 1024] = 0;
    scratch[tid + 2048] = 0; scratch[tid + 3072] = 0;
    __syncthreads();

    // count contributions per species
#pragma unroll
    for (int k = 0; k < 4; k++) {
        atomicAdd(&scratch[i1[k]], 1);
        atomicAdd(&scratch[i2[k]], 1);
        atomicAdd(&scratch[j1[k]], 1);
        atomicAdd(&scratch[j2[k]], 1);
    }
    __syncthreads();

    // pad counts to multiple of 4 (in place)
#pragma unroll
    for (int k = 0; k < 2; k++) {
        int s = tid + k * 1024;
        scratch[s] = (scratch[s] + 3) & ~3;
    }
    __syncthreads();

    // inclusive Hillis-Steele scan over 2048 padded counts
    {
        int* A = scratch;
        int* B = scratch + 2048;
        for (int d = 1; d < 2048; d <<= 1) {
#pragma unroll
            for (int k = 0; k < 2; k++) {
                int e = tid + k * 1024;
                int v = A[e];
                if (e >= d) v += A[e - d];
                B[e] = v;
            }
            __syncthreads();
            int* tp = A; A = B; B = tp;
        }
#pragma unroll
        for (int k = 0; k < 2; k++) {
            int e = tid + k * 1024;
            soff[e + 1] = A[e];
        }
        if (tid == 0) soff[0] = 0;
    }
    __syncthreads();

    // zero fill counters (reuse scratch[0..2048))
    scratch[tid] = 0; scratch[tid + 1024] = 0;
    __syncthreads();

    // fill CSR entries
#pragma unroll
    for (int k = 0; k < 4; k++) {
        int rr = tid + k * 1024;
        int p;
        p = soff[i1[k]] + atomicAdd(&scratch[i1[k]], 1); csr[p] = (rr << 1) | 1;
        p = soff[i2[k]] + atomicAdd(&scratch[i2[k]], 1); csr[p] = (rr << 1) | 1;
        p = soff[j1[k]] + atomicAdd(&scratch[j1[k]], 1); csr[p] = (rr << 1);
        p = soff[j2[k]] + atomicAdd(&scratch[j2[k]], 1); csr[p] = (rr << 1);
    }
    __syncthreads();

    // pad tails with dummy entries; pick up per-species loop bounds in regs
    int off0[2], off1[2];
#pragma unroll
    for (int k = 0; k < 2; k++) {
        int s = tid + k * 1024;
        int p0 = soff[s] + scratch[s];   // soff[s] + raw count
        int p1 = soff[s + 1];
        for (int p = p0; p < p1; ++p) csr[p] = (DUMMY_RATE_SLOT << 1);
        off0[k] = soff[s];
        off1[k] = p1;
    }
    if (tid == 0) rate[DUMMY_RATE_SLOT] = 0.f;

    // ---- state init ----
    float Creg[2];
#pragma unroll
    for (int k = 0; k < 2; k++) {
        int s = tid + k * 1024;
        float v = init_conc[s];
        Creg[k] = v;
        Cls[s] = fminf(fmaxf(v, 1e-8f), 1000.f);
        curve[s] = v;  // row 0
    }
    float tmin = ws[2], tmax = ws[3];
    float dt = (tmax - tmin) / (float)(RESN - 1);
    __syncthreads();

    // ---- main loop: 99 Euler steps ----
    for (int stp = 0; stp < RESN - 1; ++stp) {
        // phase 1: rates (16 independent LDS reads per thread)
#pragma unroll
        for (int k = 0; k < 4; k++) {
            int rr = tid + k * 1024;
            float rv = kpv[k] * Cls[i1[k]] * Cls[i2[k]]
                     - kmv[k] * Cls[j1[k]] * Cls[j2[k]];
            rate[rr] = rv;
        }
        __syncthreads();

        // phase 2: 4-wide gather per species
#pragma unroll
        for (int k = 0; k < 2; k++) {
            int s = tid + k * 1024;
            float acc = 0.f;
            for (int p = off0[k]; p < off1[k]; p += 4) {
                int4 e = *(const int4*)(csr + p);   // ds_read_b128 (16B aligned)
                float r0 = rate[e.x >> 1];
                float r1 = rate[e.y >> 1];
                float r2 = rate[e.z >> 1];
                float r3 = rate[e.w >> 1];
                acc += ((e.x & 1) ? -r0 : r0) + ((e.y & 1) ? -r1 : r1)
                     + ((e.z & 1) ? -r2 : r2) + ((e.w & 1) ? -r3 : r3);
            }
            Creg[k] += acc * dt;
            Cls[s] = fminf(fmaxf(Creg[k], 1e-8f), 1000.f);
            curve[(size_t)(stp + 1) * 2048 + s] = Creg[k];
        }
        __syncthreads();
    }
}

// One block per query time: lerp between the two bracketing trajectory rows.
__global__ void __launch_bounds__(256) interp_kernel(
    const float* __restrict__ t, const float* __restrict__ curve,
    const float* __restrict__ ws, float* __restrict__ out, int Cn) {
    int q = blockIdx.x;
    float tq = t[q];
    float tmin = ws[2], tmax = ws[3];
    float h = (tmax - tmin) / (float)(RESN - 1);
    float u = (tq - tmin) / h;
    int j0 = (int)floorf(u);
    if (j0 < 0) j0 = 0;
    if (j0 > RESN - 2) j0 = RESN - 2;
    float w = u - (float)j0;
    w = fminf(fmaxf(w, 0.f), 1.f);

    const float4* r0 = (const float4*)(curve + (size_t)j0 * Cn);
    const float4* r1 = (const float4*)(curve + (size_t)(j0 + 1) * Cn);
    float4* o = (float4*)(out + (size_t)q * Cn);
    int n4 = Cn >> 2;
    for (int k = threadIdx.x; k < n4; k += 256) {
        float4 a = r0[k], b = r1[k];
        float4 res;
        res.x = a.x + (b.x - a.x) * w;
        res.y = a.y + (b.y - a.y) * w;
        res.z = a.z + (b.z - a.z) * w;
        res.w = a.w + (b.w - a.w) * w;
        o[k] = res;
    }
}

extern "C" void kernel_launch(void* const* d_in, const int* in_sizes, int n_in,
                              void* d_out, int out_size, void* d_ws, size_t ws_size,
                              hipStream_t stream) {
    const float* t         = (const float*)d_in[0];
    const float* f         = (const float*)d_in[1];
    const float* r         = (const float*)d_in[2];
    const float* nu        = (const float*)d_in[3];
    const float* init_conc = (const float*)d_in[4];
    const float* t_init    = (const float*)d_in[5];
    int TQ = in_sizes[0];
    int Rn = in_sizes[1];
    int Cn = in_sizes[4];
    int TN = in_sizes[5];

    float* ws = (float*)d_ws;
    float* curve = ws + 16 + 6 * (size_t)Rn;

    hipLaunchKernelGGL(scalars_kernel, dim3(1), dim3(256), 0, stream,
                       init_conc, Cn, t_init, TN, ws);
    hipLaunchKernelGGL(extract_kernel, dim3(Rn), dim3(256), 0, stream,
                       nu, f, r, Rn, Cn, TN, ws);
    hipLaunchKernelGGL(integrate_kernel, dim3(1), dim3(1024), 0, stream,
                       init_conc, Cn, Rn, ws, curve);
    hipLaunchKernelGGL(interp_kernel, dim3(TQ), dim3(256), 0, stream,
                       t, curve, ws, (float*)d_out, Cn);
}

// Round 3
// 408.819 us; speedup vs baseline: 5.2934x; 1.1220x over previous
//
#include <hip/hip_runtime.h>

#define RESN 100
#define BETAC 0.1f

// ws layout (floats):
// [0]=S (sum init_conc), [1]=maxdiff(t_init), [2]=tmin, [3]=tmax
// [16 .. 16+R)          kp
// [16+R .. 16+2R)       km
// [16+2R .. 16+6R)      idx (int4 per row: neg0, neg1, pos0, pos1)
// [16+6R .. +RESN*C)    curve (RESN x C)

__global__ void scalars_kernel(const float* __restrict__ init_conc, int Cn,
                               const float* __restrict__ t_init, int TN,
                               float* __restrict__ ws) {
    __shared__ float red[256];
    int tid = threadIdx.x;

    float s = 0.f;
    for (int i = tid; i < Cn; i += 256) s += init_conc[i];
    red[tid] = s; __syncthreads();
    for (int o = 128; o; o >>= 1) { if (tid < o) red[tid] += red[tid + o]; __syncthreads(); }
    float S = red[0]; __syncthreads();

    float md = -1e30f;
    for (int i = tid; i < TN - 1; i += 256) md = fmaxf(md, t_init[i + 1] - t_init[i]);
    red[tid] = md; __syncthreads();
    for (int o = 128; o; o >>= 1) { if (tid < o) red[tid] = fmaxf(red[tid], red[tid + o]); __syncthreads(); }
    float MD = red[0]; __syncthreads();

    float mn = 1e30f;
    for (int i = tid; i < TN; i += 256) mn = fminf(mn, t_init[i]);
    red[tid] = mn; __syncthreads();
    for (int o = 128; o; o >>= 1) { if (tid < o) red[tid] = fminf(red[tid], red[tid + o]); __syncthreads(); }
    float TMIN = red[0]; __syncthreads();

    float mx = -1e30f;
    for (int i = tid; i < TN; i += 256) mx = fmaxf(mx, t_init[i]);
    red[tid] = mx; __syncthreads();
    for (int o = 128; o; o >>= 1) { if (tid < o) red[tid] = fmaxf(red[tid], red[tid + o]); __syncthreads(); }
    float TMAX = red[0];

    if (tid == 0) { ws[0] = S; ws[1] = MD; ws[2] = TMIN; ws[3] = TMAX; }
}

// One block per reaction row: find the 2 reactant (nu<0) and 2 product (nu>0)
// columns, compute order sums, then kp/km via smooth_clamp.
__global__ void extract_kernel(const float* __restrict__ nu,
                               const float* __restrict__ f,
                               const float* __restrict__ r,
                               int Rn, int Cn, int TN,
                               float* __restrict__ ws) {
    int row = blockIdx.x;
    int tid = threadIdx.x;
    __shared__ int cntn, cntp;
    __shared__ int negi[2], posi[2];
    __shared__ float red[256];
    if (tid == 0) { cntn = 0; cntp = 0; }
    __syncthreads();

    float sp = 0.f, sn = 0.f;
    const float* nr = nu + (size_t)row * Cn;
    for (int c = tid; c < Cn; c += 256) {
        float v = nr[c];
        if (v < 0.f) {
            int p = atomicAdd(&cntn, 1);
            if (p < 2) negi[p] = c;
            sn -= v;
        } else if (v > 0.f) {
            int p = atomicAdd(&cntp, 1);
            if (p < 2) posi[p] = c;
            sp += v;
        }
    }
    red[tid] = sp; __syncthreads();
    for (int o = 128; o; o >>= 1) { if (tid < o) red[tid] += red[tid + o]; __syncthreads(); }
    float order_f = red[0]; __syncthreads();
    red[tid] = sn; __syncthreads();
    for (int o = 128; o; o >>= 1) { if (tid < o) red[tid] += red[tid + o]; __syncthreads(); }
    float order_r = red[0]; __syncthreads();

    if (tid == 0) {
        float S = ws[0], MD = ws[1];
        float base = (float)TN * 10.0f / MD;
        float ub0 = base / powf(S, order_f - 1.0f);
        float ub1 = base / powf(S, order_r - 1.0f);
        float kp = ub0 / (1.0f + expf(-BETAC * (f[row] - 0.5f * ub0)));
        float km = ub1 / (1.0f + expf(-BETAC * (r[row] - 0.5f * ub1)));
        ws[16 + row] = kp;
        ws[16 + Rn + row] = km;
        int* idx = (int*)(ws + 16 + 2 * Rn);
        idx[4 * row + 0] = negi[0];
        idx[4 * row + 1] = negi[1];
        idx[4 * row + 2] = posi[0];
        idx[4 * row + 3] = posi[1];
    }
}

// Single-block Euler integration, scatter-signed-rate formulation:
// phase 1: each reaction writes +/-rate*dt into its 4 pre-assigned CSR slots
//          (slot positions live in registers; no id array in the hot loop).
// phase 2: each species sums its contiguous slot range via ds_read_b128.
// Pad slots are zeroed once and never written (sum as 0).
#define NSLOTS 22532

__global__ void __launch_bounds__(1024) integrate_kernel(
    const float* __restrict__ init_conc, int Cn, int Rn,
    const float* __restrict__ ws, float* __restrict__ curve) {
    __shared__ __align__(16) float slots[NSLOTS];
    __shared__ __align__(16) float Cls[2048];
    __shared__ int soff[2049];
    __shared__ int cntA[2048];
    __shared__ int scanB[2048];

    int tid = threadIdx.x;

    const int4*  idx4   = (const int4*)(ws + 16 + 2 * Rn);
    const float* kp_arr = ws + 16;
    const float* km_arr = ws + 16 + Rn;

    float tmin = ws[2], tmax = ws[3];
    float dt = (tmax - tmin) / (float)(RESN - 1);

    int i1[4], i2[4], j1[4], j2[4];
    float kpv[4], kmv[4];
#pragma unroll
    for (int k = 0; k < 4; k++) {
        int rr = tid + k * 1024;
        int4 v = idx4[rr];
        i1[k] = v.x; i2[k] = v.y; j1[k] = v.z; j2[k] = v.w;
        kpv[k] = kp_arr[rr] * dt;   // fold dt into the rate constants
        kmv[k] = km_arr[rr] * dt;
    }

    // ---- setup: count, pad, scan, assign slots ----
    cntA[tid] = 0; cntA[tid + 1024] = 0;
    __syncthreads();
#pragma unroll
    for (int k = 0; k < 4; k++) {
        atomicAdd(&cntA[i1[k]], 1);
        atomicAdd(&cntA[i2[k]], 1);
        atomicAdd(&cntA[j1[k]], 1);
        atomicAdd(&cntA[j2[k]], 1);
    }
    __syncthreads();
#pragma unroll
    for (int k = 0; k < 2; k++) {
        int s = tid + k * 1024;
        cntA[s] = (cntA[s] + 3) & ~3;   // pad to multiple of 4
    }
    __syncthreads();

    // inclusive Hillis-Steele scan over 2048 padded counts (ping-pong)
    {
        int* A = cntA;
        int* B = scanB;
        for (int d = 1; d < 2048; d <<= 1) {
#pragma unroll
            for (int k = 0; k < 2; k++) {
                int e = tid + k * 1024;
                int v = A[e];
                if (e >= d) v += A[e - d];
                B[e] = v;
            }
            __syncthreads();
            int* tp = A; A = B; B = tp;
        }
#pragma unroll
        for (int k = 0; k < 2; k++) {
            int e = tid + k * 1024;
            soff[e + 1] = A[e];
        }
        if (tid == 0) soff[0] = 0;
    }
    __syncthreads();

    // re-zero counters for the fill pass
    cntA[tid] = 0; cntA[tid + 1024] = 0;
    __syncthreads();

    // assign slot positions (kept in registers)
    int s0[4], s1[4], s2[4], s3[4];
#pragma unroll
    for (int k = 0; k < 4; k++) {
        s0[k] = soff[i1[k]] + atomicAdd(&cntA[i1[k]], 1);
        s1[k] = soff[i2[k]] + atomicAdd(&cntA[i2[k]], 1);
        s2[k] = soff[j1[k]] + atomicAdd(&cntA[j1[k]], 1);
        s3[k] = soff[j2[k]] + atomicAdd(&cntA[j2[k]], 1);
    }

    // zero all slots once (pads stay 0 forever)
    for (int p = tid; p < NSLOTS; p += 1024) slots[p] = 0.f;

    // per-species loop bounds in registers
    int off0[2], off1[2];
#pragma unroll
    for (int k = 0; k < 2; k++) {
        int s = tid + k * 1024;
        off0[k] = soff[s];
        off1[k] = soff[s + 1];
    }

    // ---- state init ----
    float Creg[2];
#pragma unroll
    for (int k = 0; k < 2; k++) {
        int s = tid + k * 1024;
        float v = init_conc[s];
        Creg[k] = v;
        Cls[s] = fminf(fmaxf(v, 1e-8f), 1000.f);
        curve[s] = v;  // row 0
    }
    __syncthreads();

    // ---- main loop: 99 Euler steps ----
    for (int stp = 0; stp < RESN - 1; ++stp) {
        // phase 1: compute rates, scatter signed rate*dt into slots
#pragma unroll
        for (int k = 0; k < 4; k++) {
            float rv = kpv[k] * Cls[i1[k]] * Cls[i2[k]]
                     - kmv[k] * Cls[j1[k]] * Cls[j2[k]];
            slots[s0[k]] = -rv;
            slots[s1[k]] = -rv;
            slots[s2[k]] =  rv;
            slots[s3[k]] =  rv;
        }
        __syncthreads();

        // phase 2: contiguous b128 reduction per species
#pragma unroll
        for (int k = 0; k < 2; k++) {
            int s = tid + k * 1024;
            float acc = 0.f;
            for (int p = off0[k]; p < off1[k]; p += 4) {
                float4 v = *(const float4*)(slots + p);
                acc += (v.x + v.y) + (v.z + v.w);
            }
            Creg[k] += acc;                       // dt already folded in
            Cls[s] = fminf(fmaxf(Creg[k], 1e-8f), 1000.f);
            curve[(size_t)(stp + 1) * 2048 + s] = Creg[k];
        }
        __syncthreads();
    }
}

// One block per query time: lerp between the two bracketing trajectory rows.
__global__ void __launch_bounds__(256) interp_kernel(
    const float* __restrict__ t, const float* __restrict__ curve,
    const float* __restrict__ ws, float* __restrict__ out, int Cn) {
    int q = blockIdx.x;
    float tq = t[q];
    float tmin = ws[2], tmax = ws[3];
    float h = (tmax - tmin) / (float)(RESN - 1);
    float u = (tq - tmin) / h;
    int j0 = (int)floorf(u);
    if (j0 < 0) j0 = 0;
    if (j0 > RESN - 2) j0 = RESN - 2;
    float w = u - (float)j0;
    w = fminf(fmaxf(w, 0.f), 1.f);

    const float4* r0 = (const float4*)(curve + (size_t)j0 * Cn);
    const float4* r1 = (const float4*)(curve + (size_t)(j0 + 1) * Cn);
    float4* o = (float4*)(out + (size_t)q * Cn);
    int n4 = Cn >> 2;
    for (int k = threadIdx.x; k < n4; k += 256) {
        float4 a = r0[k], b = r1[k];
        float4 res;
        res.x = a.x + (b.x - a.x) * w;
        res.y = a.y + (b.y - a.y) * w;
        res.z = a.z + (b.z - a.z) * w;
        res.w = a.w + (b.w - a.w) * w;
        o[k] = res;
    }
}

extern "C" void kernel_launch(void* const* d_in, const int* in_sizes, int n_in,
                              void* d_out, int out_size, void* d_ws, size_t ws_size,
                              hipStream_t stream) {
    const float* t         = (const float*)d_in[0];
    const float* f         = (const float*)d_in[1];
    const float* r         = (const float*)d_in[2];
    const float* nu        = (const float*)d_in[3];
    const float* init_conc = (const float*)d_in[4];
    const float* t_init    = (const float*)d_in[5];
    int TQ = in_sizes[0];
    int Rn = in_sizes[1];
    int Cn = in_sizes[4];
    int TN = in_sizes[5];

    float* ws = (float*)d_ws;
    float* curve = ws + 16 + 6 * (size_t)Rn;

    hipLaunchKernelGGL(scalars_kernel, dim3(1), dim3(256), 0, stream,
                       init_conc, Cn, t_init, TN, ws);
    hipLaunchKernelGGL(extract_kernel, dim3(Rn), dim3(256), 0, stream,
                       nu, f, r, Rn, Cn, TN, ws);
    hipLaunchKernelGGL(integrate_kernel, dim3(1), dim3(1024), 0, stream,
                       init_conc, Cn, Rn, ws, curve);
    hipLaunchKernelGGL(interp_kernel, dim3(TQ), dim3(256), 0, stream,
                       t, curve, ws, (float*)d_out, Cn);
}